// Round 6
// baseline (1191.629 us; speedup 1.0000x reference)
//
#include <hip/hip_runtime.h>

#define GRP 8
#define SUBD 64
#define NCODE 1024
#define TLEN 4096
#define NBATCH 8
#define NVEC (NBATCH * TLEN)          // 32768
#define QOUT (NBATCH * 512 * TLEN)    // 16777216
#define ROWS 64                       // x rows per block

// ws layout (bytes):
// [0]        double lossAcc[2]
// [16]       float e2[2*GRP*NCODE]            64 KB
// [65552]    int idx1[GRP*NVEC]               1 MB
// [1114128]  float cbT1[GRP*SUBD*NCODE]       2 MB   [g][d][k]
// [3211280]  float cbT2[GRP*SUBD*NCODE]       2 MB
#define WS_E2   16
#define WS_IDX1 (16 + 65536)
#define WS_CBT1 (WS_IDX1 + 1048576)
#define WS_CBT2 (WS_CBT1 + 2097152)

typedef const __attribute__((address_space(1))) char GCHAR;
typedef __attribute__((address_space(3))) char LCHAR;

__global__ __launch_bounds__(256) void k_e2(const float* __restrict__ cb1,
                                            const float* __restrict__ cb2,
                                            float* __restrict__ e2) {
    int i = blockIdx.x * 256 + threadIdx.x;      // 0 .. 16383
    const float* c = (i < GRP * NCODE) ? (cb1 + (size_t)i * SUBD)
                                       : (cb2 + (size_t)(i - GRP * NCODE) * SUBD);
    float s = 0.f;
#pragma unroll
    for (int d = 0; d < SUBD; ++d) s = __builtin_fmaf(c[d], c[d], s);
    e2[i] = s;
}

// cbT[g][d][k] = cb[g][k][d]
__global__ __launch_bounds__(256) void k_tr(const float* __restrict__ cb1,
                                            const float* __restrict__ cb2,
                                            float* __restrict__ cbT1,
                                            float* __restrict__ cbT2) {
    int i = blockIdx.x * 256 + threadIdx.x;      // 0 .. 16383
    int sel = i >> 13, g = (i >> 10) & 7, k = i & 1023;
    const float* src = (sel ? cb2 : cb1) + ((size_t)g * NCODE + k) * SUBD;
    float* dst = (sel ? cbT2 : cbT1) + (size_t)g * SUBD * NCODE + k;
#pragma unroll
    for (int s = 0; s < 16; ++s) {
        float4 v = ((const float4*)src)[s];
#pragma unroll
        for (int dd = 0; dd < 4; ++dd) dst[(size_t)(4 * s + dd) * NCODE] = ((const float*)&v)[dd];
    }
}

// Block: 256 thr = 4 waves over 64 rows; wave w searches codes [w*256,(w+1)*256).
// Lane: rg=lane&15 -> rows n0=rg*4 (4 rows), kgr=lane>>4 -> 8 codes per chunk
// (k = w*256 + c*32 + kgr*8 + j), 8 chunks. acc[4][8] per lane.
// Exactness: every xe is one ascending-d fma chain; dist = fma(-2,acc,fl(x2+e2));
// per-lane k ascending (strict <); in-wave reduce lexicographic (dist,k);
// cross-wave merge scans waves ascending with strict < == first-index argmin.
template <int STAGE2>
__global__ __launch_bounds__(256, 4) void k_vq(
    const float* __restrict__ x,
    const float* __restrict__ cb1,
    const float* __restrict__ cb2,
    const float* __restrict__ cbT,      // transposed codebook to search
    const float* __restrict__ e2,       // e2 row for this codebook (8*1024)
    const int* __restrict__ idxPrev,    // idx1 (stage2)
    int* __restrict__ idxOut,           // idx1 (stage1)
    float* __restrict__ outIdxF,
    float* __restrict__ qout,           // stage2
    double* __restrict__ lossAcc)       // stage2
{
    __shared__ __align__(16) float xs[SUBD * ROWS];   // 16 KB, [d][row]
    __shared__ __align__(16) float e2u[1024];         // e2 slab; later bdH/biH
    __shared__ __align__(16) float x2s[ROWS];
    __shared__ int i2s[ROWS];
    __shared__ double wsr[8];

    const int tid = threadIdx.x, w = tid >> 6, lane = tid & 63;
    const int g = blockIdx.y, bz = blockIdx.z;
    const int t0 = blockIdx.x * ROWS;
    const float* xsrc = x + ((size_t)(bz * 512 + g * SUBD)) * TLEN + t0;

    // ---- stage x tile (d-major, linear dest) + e2 slab via global_load_lds ----
    {
#pragma unroll
        for (int q = 0; q < 4; ++q) {
            int inst = w * 4 + q;                     // 0..15; floats [inst*256,+256)
            int d = inst * 4 + (lane >> 4);
            const float* gp = xsrc + (size_t)d * TLEN + (lane & 15) * 4;
            float* lp = xs + inst * 256;              // wave-uniform base
            __builtin_amdgcn_global_load_lds((GCHAR*)gp, (LCHAR*)lp, 16, 0, 0);
        }
        const float* ep = e2 + g * NCODE + w * 256 + lane * 4;
        float* lp = e2u + w * 256;
        __builtin_amdgcn_global_load_lds((GCHAR*)ep, (LCHAR*)lp, 16, 0, 0);
    }
    __syncthreads();

    // ---- stage2: residual update + loss1, 256-thread-wide (16 d per thread) ----
    const int row = tid & 63, dq = tid >> 6;          // d in [dq*16, dq*16+16)
    double ls1 = 0.0;
    int i1 = 0;
    if (STAGE2) {
        int nv = bz * TLEN + t0 + row;
        i1 = idxPrev[g * NVEC + nv];
        const float4* z1v = (const float4*)(cb1 + ((size_t)g * NCODE + i1) * SUBD) + dq * 4;
#pragma unroll
        for (int s = 0; s < 4; ++s) {
            float4 z = z1v[s];
#pragma unroll
            for (int dd = 0; dd < 4; ++dd) {
                int d = dq * 16 + s * 4 + dd;
                float r = xs[d * ROWS + row];
                float zz = ((const float*)&z)[dd];
                float tt = zz - r;            // fl(z - r)   (loss1 term)
                float zst = r + tt;           // fl(r + tt)
                ls1 += (double)(tt * tt);
                float r2 = r - zst;           // fl(r - zst) -> residual2
                xs[d * ROWS + row] = r2;
            }
        }
        __syncthreads();
    }

    // ---- x2: single ascending-d fma chain per row (tid<64) ----
    if (tid < ROWS) {
        float xx = 0.f;
#pragma unroll
        for (int d = 0; d < SUBD; ++d) {
            float r = xs[d * ROWS + tid];
            xx = __builtin_fmaf(r, r, xx);
        }
        x2s[tid] = xx;
    }
    __syncthreads();

    // ---- GEMM + argmin ----
    const int rg = lane & 15, kgr = lane >> 4;
    const int n0 = rg * 4;

    float x2r[4];
    {
        float4 a = *(const float4*)(x2s + n0);
#pragma unroll
        for (int i = 0; i < 4; ++i) x2r[i] = ((const float*)&a)[i];
    }

    float best[4];
    int bidx[4];
#pragma unroll
    for (int i = 0; i < 4; ++i) { best[i] = 1e30f; bidx[i] = 0; }

    const float* cbTg = cbT + (size_t)g * SUBD * NCODE;   // [d][1024]

    for (int c = 0; c < 8; ++c) {
        const int kb = w * 256 + c * 32 + kgr * 8;
        const float* cp = cbTg + kb;
        float acc[4][8];
#pragma unroll
        for (int i = 0; i < 4; ++i)
#pragma unroll
            for (int j = 0; j < 8; ++j) acc[i][j] = 0.f;

#pragma unroll 4
        for (int d = 0; d < SUBD; ++d) {
            float4 xa = *(const float4*)(xs + d * ROWS + n0);
            float4 c0 = *(const float4*)(cp + d * NCODE);
            float4 c1 = *(const float4*)(cp + d * NCODE + 4);
#pragma unroll
            for (int i = 0; i < 4; ++i) {
                float xv = ((const float*)&xa)[i];
#pragma unroll
                for (int j = 0; j < 4; ++j) {
                    acc[i][j]     = __builtin_fmaf(xv, ((const float*)&c0)[j], acc[i][j]);
                    acc[i][j + 4] = __builtin_fmaf(xv, ((const float*)&c1)[j], acc[i][j + 4]);
                }
            }
        }

        float4 e0 = *(const float4*)(e2u + kb);
        float4 e1 = *(const float4*)(e2u + kb + 4);
#pragma unroll
        for (int j = 0; j < 8; ++j) {
            float e2k = (j < 4) ? ((const float*)&e0)[j] : ((const float*)&e1)[j - 4];
            int k = kb + j;
#pragma unroll
            for (int i = 0; i < 4; ++i) {
                float tv = x2r[i] + e2k;                            // fl(x2 + e2)
                float dist = __builtin_fmaf(-2.0f, acc[i][j], tv);  // fl(tv - 2a)
                if (dist < best[i]) { best[i] = dist; bidx[i] = k; }  // ascending k
            }
        }
    }

    // ---- lexicographic reduce across kgr lanes (bits 4..5) ----
#pragma unroll
    for (int i = 0; i < 4; ++i) {
        float bd = best[i];
        int bi = bidx[i];
#pragma unroll
        for (int m = 16; m < 64; m <<= 1) {
            float od = __shfl_xor(bd, m, 64);
            int oi = __shfl_xor(bi, m, 64);
            if (od < bd || (od == bd && oi < bi)) { bd = od; bi = oi; }
        }
        best[i] = bd; bidx[i] = bi;
    }

    __syncthreads();                       // all waves done reading e2u
    float* bdH = e2u;                      // [4][64]
    int* biH = (int*)(e2u + 256);          // [4][64]
    if (kgr == 0) {
#pragma unroll
        for (int i = 0; i < 4; ++i) {
            bdH[w * ROWS + n0 + i] = best[i];
            biH[w * ROWS + n0 + i] = bidx[i];
        }
    }
    __syncthreads();

    // ---- cross-wave merge (ascending wave = ascending k; strict <) ----
    if (tid < ROWS) {
        float bd = bdH[tid];
        int bi = biH[tid];
#pragma unroll
        for (int wv = 1; wv < 4; ++wv) {
            float od = bdH[wv * ROWS + tid];
            int oi = biH[wv * ROWS + tid];
            if (od < bd) { bd = od; bi = oi; }
        }
        int n = bz * TLEN + t0 + tid;
        outIdxF[(size_t)g * NVEC + n] = (float)bi;
        if (!STAGE2) idxOut[g * NVEC + n] = bi;
        else i2s[tid] = bi;
    }

    // ---- stage2 fused epilogue: 256-thread-wide output + loss2 ----
    double ls2 = 0.0;
    if (STAGE2) {
        __syncthreads();
        int bi = i2s[row];
        const float4* z1v = (const float4*)(cb1 + ((size_t)g * NCODE + i1) * SUBD) + dq * 4;
        const float4* z2v = (const float4*)(cb2 + ((size_t)g * NCODE + bi) * SUBD) + dq * 4;
        const float* xp = xsrc + row;
        float* op = qout + ((size_t)(bz * 512 + g * SUBD)) * TLEN + t0 + row;
#pragma unroll
        for (int s = 0; s < 4; ++s) {
            float4 z1 = z1v[s];
            float4 z2 = z2v[s];
#pragma unroll
            for (int dd = 0; dd < 4; ++dd) {
                int d = dq * 16 + s * 4 + dd;
                float xv = xp[(size_t)d * TLEN];
                float r2 = xs[d * ROWS + row];     // residual2 (bit-exact)
                float z1f = ((const float*)&z1)[dd];
                float z2f = ((const float*)&z2)[dd];
                float t1 = z1f - xv;
                float zst1 = xv + t1;
                float t2 = z2f - r2;               // fl(z2 - r2) (loss2)
                float zst2 = r2 + t2;
                float q = zst1 + zst2;             // fl(zst1 + zst2)
                op[(size_t)d * TLEN] = q;
                ls2 += (double)(t2 * t2);
            }
        }

        // block reduce both losses, 2 atomics per block
#pragma unroll
        for (int off = 32; off; off >>= 1) {
            ls1 += __shfl_down(ls1, off, 64);
            ls2 += __shfl_down(ls2, off, 64);
        }
        if (lane == 0) { wsr[w] = ls1; wsr[4 + w] = ls2; }
        __syncthreads();
        if (tid == 0)
            atomicAdd(lossAcc + 0, wsr[0] + wsr[1] + wsr[2] + wsr[3]);
        else if (tid == 64)
            atomicAdd(lossAcc + 1, wsr[4] + wsr[5] + wsr[6] + wsr[7]);
    }
}

__global__ void k_final(float* __restrict__ lossOut, const double* __restrict__ lossAcc) {
    // loss_i = 1.25 * mean_i ; total = (l1+l2)/2 = 0.625*(m1+m2)
    double m = (lossAcc[0] + lossAcc[1]) / (double)QOUT;
    lossOut[0] = (float)(0.625 * m);
}

extern "C" void kernel_launch(void* const* d_in, const int* in_sizes, int n_in,
                              void* d_out, int out_size, void* d_ws, size_t ws_size,
                              hipStream_t stream) {
    const float* x   = (const float*)d_in[0];
    const float* cb1 = (const float*)d_in[1];
    const float* cb2 = (const float*)d_in[2];
    float* out = (float*)d_out;

    char* ws = (char*)d_ws;
    double* lossAcc = (double*)ws;
    float* e2   = (float*)(ws + WS_E2);
    int*   idx1 = (int*)(ws + WS_IDX1);
    float* cbT1 = (float*)(ws + WS_CBT1);
    float* cbT2 = (float*)(ws + WS_CBT2);

    hipMemsetAsync(ws, 0, 16, stream);

    k_e2<<<dim3(64), dim3(256), 0, stream>>>(cb1, cb2, e2);
    k_tr<<<dim3(64), dim3(256), 0, stream>>>(cb1, cb2, cbT1, cbT2);

    dim3 grid(TLEN / ROWS, GRP, NBATCH);                   // (64, 8, 8) = 4096
    float* outIdx = out + QOUT + 1;
    k_vq<0><<<grid, dim3(256), 0, stream>>>(x, cb1, cb2, cbT1, e2,
                                            nullptr, idx1, outIdx, nullptr, nullptr);
    k_vq<1><<<grid, dim3(256), 0, stream>>>(x, cb1, cb2, cbT2, e2 + GRP * NCODE,
                                            idx1, nullptr, outIdx + (size_t)GRP * NVEC,
                                            out, lossAcc);
    k_final<<<1, 1, 0, stream>>>(out + QOUT, lossAcc);
}

// Round 9
// 921.825 us; speedup vs baseline: 1.2927x; 1.2927x over previous
//
#include <hip/hip_runtime.h>

#define GRP 8
#define SUBD 64
#define NCODE 1024
#define TLEN 4096
#define NBATCH 8
#define NVEC (NBATCH * TLEN)          // 32768
#define QOUT (NBATCH * 512 * TLEN)    // 16777216
#define ROWS 128                      // rows per block
#define NGRPS (NCODE / 8)             // 128 groups of 8 codes

// ws layout (bytes):
// [0]       double lossAcc[2]
// [64]      float e2[2][8][1024]              64 KB
// [65600]   int idx1[8*32768]                 1 MB
// [1114176] float cbP1[8][128][64][8]         2 MB   panel [g][grp][d][8j]
// [3211328] float cbP2[...]                   2 MB
#define WS_E2   64
#define WS_IDX1 (WS_E2 + 65536)
#define WS_P1   (WS_IDX1 + 1048576)
#define WS_P2   (WS_P1 + 2097152)

typedef const __attribute__((address_space(1))) char GCHAR;
typedef __attribute__((address_space(3))) char LCHAR;

__global__ __launch_bounds__(256) void k_e2(const float* __restrict__ cb1,
                                            const float* __restrict__ cb2,
                                            float* __restrict__ e2) {
    int i = blockIdx.x * 256 + threadIdx.x;      // 0 .. 16383
    const float* c = (i < GRP * NCODE) ? (cb1 + (size_t)i * SUBD)
                                       : (cb2 + (size_t)(i - GRP * NCODE) * SUBD);
    float s = 0.f;
#pragma unroll
    for (int d = 0; d < SUBD; ++d) s = __builtin_fmaf(c[d], c[d], s);
    e2[i] = s;
}

// Panel repack (verified in r4, absmax 0.0): cbP[g][grp][d][j] = cb[g][grp*8+j][d]
__global__ __launch_bounds__(256) void k_panel(const float* __restrict__ cb1,
                                               const float* __restrict__ cb2,
                                               float* __restrict__ cbP1,
                                               float* __restrict__ cbP2) {
    int i = blockIdx.x * 256 + threadIdx.x;      // 0 .. 16383
    int sel = i >> 13, rest = i & 8191, g = rest >> 10, k = rest & 1023;
    int grp = k >> 3, j = k & 7;
    const float* src = (sel ? cb2 : cb1) + ((size_t)g * NCODE + k) * SUBD;
    float* dst = (sel ? cbP2 : cbP1) + ((size_t)(g * NGRPS + grp) * SUBD) * 8 + j;
#pragma unroll
    for (int s = 0; s < 16; ++s) {
        float4 v = ((const float4*)src)[s];
#pragma unroll
        for (int dd = 0; dd < 4; ++dd) dst[(4 * s + dd) * 8] = ((const float*)&v)[dd];
    }
}

// Block: 256 thr = 4 waves over 128 rows. Wave w: code-half (w&1), rows
// (w>>1)*64 + lane (one ROW PER LANE). Codes + e2 are wave-uniform (SGPR via
// readfirstlane) -> s_load; x from LDS d-major (imm-offset ds_read_b32).
// Per d: 1 ds_read + 32 fma (acc[4][8] over 4 grps of 8 codes).
// Exactness: per (row,code) one ascending-d fma chain; dist = fma(-2,acc,
// fl(x2+e2)); per-thread k ascending, strict <; half-merge prefers half 0 on
// ties (lower k) == reference first-index argmin. All elementwise expressions
// verbatim from absmax=0 rounds.
template <int STAGE2>
__global__ __launch_bounds__(256, 4) void k_vq(
    const float* __restrict__ x,
    const float* __restrict__ cb1,
    const float* __restrict__ cb2,
    const float* __restrict__ cbP,      // packed panel for search codebook
    const float* __restrict__ e2,       // e2 row for search codebook (8*1024)
    const int* __restrict__ idxPrev,    // idx1 (stage2)
    int* __restrict__ idxOut,           // idx1 (stage1)
    float* __restrict__ outIdxF,
    float* __restrict__ qout,           // stage2
    double* __restrict__ lossAcc)       // stage2
{
    __shared__ __align__(16) float xs[SUBD * ROWS];   // 32 KB [d][row]
    __shared__ float bdH[2 * ROWS];
    __shared__ int   biH[2 * ROWS];
    __shared__ int   i2s[ROWS];
    __shared__ double wsr[8];

    const int tid = threadIdx.x, w = tid >> 6, lane = tid & 63;
    const int g = blockIdx.y;
    const int row0 = blockIdx.x * ROWS;
    const int bz = row0 / TLEN, t0 = row0 % TLEN;
    const float* xsrc = x + ((size_t)(bz * 512 + g * SUBD)) * TLEN + t0;

    // ---- stage x tile (d-major, linear dest) via global_load_lds (r5 verbatim) ----
    {
#pragma unroll
        for (int q = 0; q < 8; ++q) {
            int inst = w * 8 + q;                 // 0..31, 2 d-rows each
            int d = inst * 2 + (lane >> 5);
            const float* gp = xsrc + (size_t)d * TLEN + (lane & 31) * 4;
            float* lp = xs + inst * 256;          // wave-uniform base
            __builtin_amdgcn_global_load_lds((GCHAR*)gp, (LCHAR*)lp, 16, 0, 0);
        }
    }
    __syncthreads();

    // ---- stage2: residual update + loss1 (256-wide: row=tid&127, hi=tid>>7) ----
    const int rowB = tid & 127, hi = tid >> 7;
    double ls1 = 0.0;
    int i1 = 0;
    if (STAGE2) {
        i1 = idxPrev[g * NVEC + row0 + rowB];
        const float4* z1v = (const float4*)(cb1 + ((size_t)g * NCODE + i1) * SUBD) + hi * 8;
#pragma unroll
        for (int s = 0; s < 8; ++s) {
            float4 z = z1v[s];
#pragma unroll
            for (int dd = 0; dd < 4; ++dd) {
                int d = hi * 32 + s * 4 + dd;
                float r = xs[d * ROWS + rowB];
                float zz = (&z.x)[dd];
                float tt = zz - r;            // fl(z - r)   (loss1 term)
                float zst = r + tt;           // fl(r + tt)
                ls1 += (double)(tt * tt);
                float r2 = r - zst;           // fl(r - zst) -> residual2
                xs[d * ROWS + rowB] = r2;
            }
        }
        __syncthreads();
    }

    // ---- GEMM + argmin (row per lane; codes wave-uniform -> SGPR) ----
    const int w_u = __builtin_amdgcn_readfirstlane(w);
    const int half = w_u & 1;
    const int row = (w_u >> 1) * 64 + lane;

    float x2 = 0.f;
#pragma unroll 8
    for (int d = 0; d < SUBD; ++d) {
        float r = xs[d * ROWS + row];
        x2 = __builtin_fmaf(r, r, x2);        // ascending-d chain
    }

    const float* cph = cbP + (size_t)g * (NGRPS * SUBD * 8) + (size_t)(half * 64) * (SUBD * 8);
    const float* e2h = e2 + g * NCODE + half * 512;

    float best = 1e30f;
    int bidx = 0;
    for (int ib = 0; ib < 16; ++ib) {
        const float* cp = cph + ib * 4 * (SUBD * 8);
        float acc[4][8];
#pragma unroll
        for (int gg = 0; gg < 4; ++gg)
#pragma unroll
            for (int j = 0; j < 8; ++j) acc[gg][j] = 0.f;

#pragma unroll 4
        for (int d = 0; d < SUBD; ++d) {
            float xv = xs[d * ROWS + row];
#pragma unroll
            for (int gg = 0; gg < 4; ++gg) {
                const float* cb8 = cp + gg * (SUBD * 8) + d * 8;
#pragma unroll
                for (int j = 0; j < 8; ++j)
                    acc[gg][j] = __builtin_fmaf(xv, cb8[j], acc[gg][j]);   // ascending d
            }
        }

#pragma unroll
        for (int gg = 0; gg < 4; ++gg) {
            const float* ep = e2h + (ib * 4 + gg) * 8;
#pragma unroll
            for (int j = 0; j < 8; ++j) {
                int k = half * 512 + (ib * 4 + gg) * 8 + j;
                float tv = x2 + ep[j];                              // fl(x2 + e2)
                float dist = __builtin_fmaf(-2.0f, acc[gg][j], tv); // fl(tv - 2a)
                if (dist < best) { best = dist; bidx = k; }         // ascending k
            }
        }
    }
    bdH[half * ROWS + row] = best;
    biH[half * ROWS + row] = bidx;
    __syncthreads();

    // ---- half-merge (half0 wins ties -> lower k), outputs ----
    if (!(w_u & 1)) {
        float d0 = bdH[row];
        int   k0 = biH[row];
        float d1 = bdH[ROWS + row];
        int   k1 = biH[ROWS + row];
        int bi = (d1 < d0) ? k1 : k0;      // strict <: tie -> half0
        int nv = row0 + row;
        outIdxF[(size_t)g * NVEC + nv] = (float)bi;
        if (!STAGE2) idxOut[g * NVEC + nv] = bi;
        else i2s[row] = bi;
    }

    // ---- stage2 fused epilogue: output + loss2 (verbatim exprs) ----
    double ls2 = 0.0;
    if (STAGE2) {
        __syncthreads();
        int bi = i2s[rowB];
        const float4* z1v = (const float4*)(cb1 + ((size_t)g * NCODE + i1) * SUBD) + hi * 8;
        const float4* z2v = (const float4*)(cb2 + ((size_t)g * NCODE + bi) * SUBD) + hi * 8;
        const float* xp = xsrc + rowB;
        float* op = qout + ((size_t)(bz * 512 + g * SUBD)) * TLEN + t0 + rowB;
#pragma unroll
        for (int s = 0; s < 8; ++s) {
            float4 z1 = z1v[s];
            float4 z2 = z2v[s];
#pragma unroll
            for (int dd = 0; dd < 4; ++dd) {
                int d = hi * 32 + s * 4 + dd;
                float xv = xp[(size_t)d * TLEN];
                float r2 = xs[d * ROWS + rowB];     // residual2 (bit-exact)
                float z1f = (&z1.x)[dd];
                float z2f = (&z2.x)[dd];
                float t1 = z1f - xv;
                float zst1 = xv + t1;
                float t2 = z2f - r2;                // fl(z2 - r2) (loss2)
                float zst2 = r2 + t2;
                float qv = zst1 + zst2;             // fl(zst1 + zst2)
                op[(size_t)d * TLEN] = qv;
                ls2 += (double)(t2 * t2);
            }
        }

        // block reduce both losses, 2 atomics per block
#pragma unroll
        for (int off = 32; off; off >>= 1) {
            ls1 += __shfl_down(ls1, off, 64);
            ls2 += __shfl_down(ls2, off, 64);
        }
        if (lane == 0) { wsr[w] = ls1; wsr[4 + w] = ls2; }
        __syncthreads();
        if (tid == 0)
            atomicAdd(lossAcc + 0, wsr[0] + wsr[1] + wsr[2] + wsr[3]);
        else if (tid == 64)
            atomicAdd(lossAcc + 1, wsr[4] + wsr[5] + wsr[6] + wsr[7]);
    }
}

__global__ void k_final(float* __restrict__ lossOut, const double* __restrict__ lossAcc) {
    // loss_i = 1.25 * mean_i ; total = (l1+l2)/2 = 0.625*(m1+m2)
    double m = (lossAcc[0] + lossAcc[1]) / (double)QOUT;
    lossOut[0] = (float)(0.625 * m);
}

extern "C" void kernel_launch(void* const* d_in, const int* in_sizes, int n_in,
                              void* d_out, int out_size, void* d_ws, size_t ws_size,
                              hipStream_t stream) {
    const float* x   = (const float*)d_in[0];
    const float* cb1 = (const float*)d_in[1];
    const float* cb2 = (const float*)d_in[2];
    float* out = (float*)d_out;

    char* ws = (char*)d_ws;
    double* lossAcc = (double*)ws;
    float* e2   = (float*)(ws + WS_E2);
    int*   idx1 = (int*)(ws + WS_IDX1);
    float* cbP1 = (float*)(ws + WS_P1);
    float* cbP2 = (float*)(ws + WS_P2);

    hipMemsetAsync(ws, 0, 16, stream);

    k_e2<<<dim3(64), dim3(256), 0, stream>>>(cb1, cb2, e2);
    k_panel<<<dim3(64), dim3(256), 0, stream>>>(cb1, cb2, cbP1, cbP2);

    dim3 grid(NVEC / ROWS, GRP);                           // (256, 8)
    float* outIdx = out + QOUT + 1;
    k_vq<0><<<grid, dim3(256), 0, stream>>>(x, cb1, cb2, cbP1, e2,
                                            nullptr, idx1, outIdx, nullptr, nullptr);
    k_vq<1><<<grid, dim3(256), 0, stream>>>(x, cb1, cb2, cbP2, e2 + GRP * NCODE,
                                            idx1, nullptr, outIdx + (size_t)GRP * NVEC,
                                            out, lossAcc);
    k_final<<<1, 1, 0, stream>>>(out + QOUT, lossAcc);
}